// Round 1
// baseline (75.317 us; speedup 1.0000x reference)
//
#include <hip/hip_runtime.h>

// RoiAlign (crop_and_resize style):
//   feature_map: (N=4, C=256, H=50, W=50) f32
//   boxes:       (M=512, 4) f32  [x1,y1,x2,y2], divided by STRIDE=16
//   box_idx:     (M=512) i32
//   out:         (M, C, 14, 14) f32
// Memory-bound on the 102.8 MB output write; fm (10.2 MB) is L3-resident.

constexpr int C_DIM = 256;
constexpr int H_DIM = 50;
constexpr int W_DIM = 50;
constexpr int M_BOX = 512;
constexpr int CH    = 14;
constexpr int CW    = 14;
constexpr float INV_STRIDE = 1.0f / 16.0f;

__global__ __launch_bounds__(256) void roi_align_f2(
    const float* __restrict__ fm,
    const float* __restrict__ boxes,
    const int*   __restrict__ box_idx,
    float*       __restrict__ out,
    int n_pairs)
{
    int tid     = blockIdx.x * blockDim.x + threadIdx.x;
    int gstride = gridDim.x * blockDim.x;

    for (int p = tid; p < n_pairs; p += gstride) {
        // p indexes float2 pairs: layout (m, c, iy, ixp) with ixp in [0,7)
        int ixp = p % 7;
        int t   = p / 7;
        int iy  = t % CH;
        t       = t / CH;
        int c   = t & (C_DIM - 1);
        int m   = t >> 8;

        float4 bx = reinterpret_cast<const float4*>(boxes)[m];
        int bi = box_idx[m];
        float x1 = bx.x * INV_STRIDE;
        float y1 = bx.y * INV_STRIDE;
        float x2 = bx.z * INV_STRIDE;
        float y2 = bx.w * INV_STRIDE;

        // y coordinate (shared by both elements of the pair) — match ref op order
        float ys  = y1 + ((float)iy * (y2 - y1)) / 13.0f;
        float y0f = floorf(ys);
        float wy  = ys - y0f;
        int y0i = (int)y0f;
        y0i = min(max(y0i, 0), H_DIM - 1);
        int y1i = min(y0i + 1, H_DIM - 1);
        bool yv = (ys >= 0.0f) && (ys <= (float)(H_DIM - 1));

        const float* plane = fm + ((size_t)bi * C_DIM + c) * (size_t)(H_DIM * W_DIM);
        const float* row0  = plane + y0i * W_DIM;
        const float* row1  = plane + y1i * W_DIM;

        float rv[2];
        #pragma unroll
        for (int k = 0; k < 2; ++k) {
            int ix    = ixp * 2 + k;
            float xs  = x1 + ((float)ix * (x2 - x1)) / 13.0f;
            float x0f = floorf(xs);
            float wx  = xs - x0f;
            int x0i = (int)x0f;
            x0i = min(max(x0i, 0), W_DIM - 1);
            int x1i = min(x0i + 1, W_DIM - 1);
            bool v  = yv && (xs >= 0.0f) && (xs <= (float)(W_DIM - 1));

            float top = row0[x0i] * (1.0f - wx) + row0[x1i] * wx;
            float bot = row1[x0i] * (1.0f - wx) + row1[x1i] * wx;
            float val = top * (1.0f - wy) + bot * wy;
            rv[k] = v ? val : 0.0f;
        }

        float2 r;
        r.x = rv[0];
        r.y = rv[1];
        reinterpret_cast<float2*>(out)[p] = r;
    }
}

extern "C" void kernel_launch(void* const* d_in, const int* in_sizes, int n_in,
                              void* d_out, int out_size, void* d_ws, size_t ws_size,
                              hipStream_t stream) {
    const float* fm      = (const float*)d_in[0];
    const float* boxes   = (const float*)d_in[1];
    const int*   box_idx = (const int*)d_in[2];
    float* out = (float*)d_out;

    int n_pairs = M_BOX * C_DIM * CH * (CW / 2);  // 12,845,056 float2 stores

    dim3 block(256);
    dim3 grid(2048);  // 32 waves/CU capacity; grid-stride covers the rest
    hipLaunchKernelGGL(roi_align_f2, grid, block, 0, stream,
                       fm, boxes, box_idx, out, n_pairs);
}

// Round 2
// 55.829 us; speedup vs baseline: 1.3491x; 1.3491x over previous
//
#include <hip/hip_runtime.h>

// RoiAlign: fm (4,256,50,50) f32, boxes (512,4), box_idx (512) -> out (512,256,14,14) f32
//
// Structure: one block = (box m, 64-channel chunk). Threads 0..195 each own one
// output position (iy,ix); coordinate/weight/offset math is computed ONCE per
// thread and amortized over the 64-channel inner loop (it is invariant in c).
// Inner loop per element: 4 gather loads + bilinear + 1 coalesced 4B store.
// Blocks of the same box are pinned to the same XCD (bid%8 partition) so the
// box's fm window is fetched into one L2, not four. Output uses nontemporal
// stores so the 102.8 MB write stream doesn't evict fm from L2.

constexpr int C_DIM  = 256;
constexpr int H_DIM  = 50;
constexpr int W_DIM  = 50;
constexpr int M_BOX  = 512;
constexpr int CH     = 14;
constexpr int CW     = 14;
constexpr int NPOS   = CH * CW;          // 196
constexpr int C_CHUNK = 64;              // channels per block
constexpr int CHUNKS  = C_DIM / C_CHUNK; // 4
constexpr int PLANE   = H_DIM * W_DIM;   // 2500
constexpr float INV_STRIDE = 1.0f / 16.0f;

__global__ __launch_bounds__(256) void roi_align_pos(
    const float* __restrict__ fm,
    const float* __restrict__ boxes,
    const int*   __restrict__ box_idx,
    float*       __restrict__ out)
{
    // XCD-affine work assignment: dispatch sends bid -> XCD (bid % 8).
    // Give each XCD 256 consecutive logical work items so a box's 4 chunks
    // (logical 4m..4m+3) stay on one XCD/L2.
    int bid     = blockIdx.x;
    int logical = (bid & 7) * ((M_BOX * CHUNKS) / 8) + (bid >> 3);
    int m       = logical >> 2;          // box
    int cbase   = (logical & 3) * C_CHUNK;

    int t = threadIdx.x;
    if (t >= NPOS) return;               // threads 196..255 idle (wave 3 mostly)

    int iy = t / CW;                     // compile-time divisor, once per thread
    int ix = t - iy * CW;

    float4 bx = reinterpret_cast<const float4*>(boxes)[m];
    int bi = box_idx[m];
    float x1 = bx.x * INV_STRIDE;
    float y1 = bx.y * INV_STRIDE;
    float x2 = bx.z * INV_STRIDE;
    float y2 = bx.w * INV_STRIDE;

    // Match reference op order: v1 + (i * (v2-v1)) / 13
    float ys = y1 + ((float)iy * (y2 - y1)) / 13.0f;
    float xs = x1 + ((float)ix * (x2 - x1)) / 13.0f;

    float y0f = floorf(ys);
    float x0f = floorf(xs);
    float wy = ys - y0f;
    float wx = xs - x0f;
    float omwy = 1.0f - wy;
    float omwx = 1.0f - wx;

    int y0i = min(max((int)y0f, 0), H_DIM - 1);
    int y1i = min(y0i + 1, H_DIM - 1);
    int x0i = min(max((int)x0f, 0), W_DIM - 1);
    int x1i = min(x0i + 1, W_DIM - 1);

    bool valid = (ys >= 0.0f) && (ys <= (float)(H_DIM - 1)) &&
                 (xs >= 0.0f) && (xs <= (float)(W_DIM - 1));

    int o00 = y0i * W_DIM + x0i;
    int o01 = y0i * W_DIM + x1i;
    int o10 = y1i * W_DIM + x0i;
    int o11 = y1i * W_DIM + x1i;

    const float* plane = fm + ((size_t)bi * C_DIM + cbase) * PLANE;
    float* op = out + ((size_t)m * C_DIM + cbase) * NPOS + t;

    #pragma unroll 4
    for (int c = 0; c < C_CHUNK; ++c) {
        float f00 = plane[o00];
        float f01 = plane[o01];
        float f10 = plane[o10];
        float f11 = plane[o11];
        float top = f00 * omwx + f01 * wx;
        float bot = f10 * omwx + f11 * wx;
        float val = top * omwy + bot * wy;
        val = valid ? val : 0.0f;
        __builtin_nontemporal_store(val, op);
        plane += PLANE;
        op    += NPOS;
    }
}

extern "C" void kernel_launch(void* const* d_in, const int* in_sizes, int n_in,
                              void* d_out, int out_size, void* d_ws, size_t ws_size,
                              hipStream_t stream) {
    const float* fm      = (const float*)d_in[0];
    const float* boxes   = (const float*)d_in[1];
    const int*   box_idx = (const int*)d_in[2];
    float* out = (float*)d_out;

    dim3 block(256);
    dim3 grid(M_BOX * CHUNKS);  // 2048 blocks x 4 waves = full occupancy
    hipLaunchKernelGGL(roi_align_pos, grid, block, 0, stream,
                       fm, boxes, box_idx, out);
}

// Round 3
// 53.825 us; speedup vs baseline: 1.3993x; 1.0372x over previous
//
#include <hip/hip_runtime.h>

// RoiAlign: fm (4,256,50,50) f32, boxes (512,4), box_idx (512) -> out (512,256,14,14) f32
//
// R3: LDS window staging. A box's bilinear taps all fall in a <=15x15 window
// (box width <= 199/16 = 12.44 fm px -> tap span <= 15). Per block
// (box, 32-channel chunk):
//   Phase A: 240 threads cooperatively load the 15x16 window of each of the
//            32 planes into LDS (coalesced 16-lane row segments; each fm line
//            touched ONCE per block instead of 4x by divergent gathers).
//   Phase B: threads 0..195 (one per output position) do 4 ds_read + bilinear
//            + NT store per plane. Coordinates computed once, reused 32x.
// XCD affinity: all 8 chunks of a box land on one XCD (bid%8 partition).
// NT stores keep the 103 MB output stream from evicting fm out of L2.

constexpr int C_DIM = 256;
constexpr int H_DIM = 50;
constexpr int W_DIM = 50;
constexpr int M_BOX = 512;
constexpr int CH    = 14;
constexpr int CW    = 14;
constexpr int NPOS  = CH * CW;        // 196
constexpr int CCH   = 32;             // channels per block
constexpr int NCHUNK = C_DIM / CCH;   // 8
constexpr int PLANE  = H_DIM * W_DIM; // 2500
constexpr int WR = 15;                // window rows
constexpr int WC = 16;                // window cols
constexpr int WSZ = 256;              // padded LDS plane stride (15*16=240 -> 256)
constexpr float INV_STRIDE = 1.0f / 16.0f;

__global__ __launch_bounds__(256) void roi_align_lds(
    const float* __restrict__ fm,
    const float* __restrict__ boxes,
    const int*   __restrict__ box_idx,
    float*       __restrict__ out)
{
    __shared__ float Wnd[CCH * WSZ];  // 32 KB

    // XCD-affine: logical work id grouped so XCD k owns boxes [64k, 64k+64),
    // all 8 chunks of a box on the same XCD/L2.
    int bid     = blockIdx.x;
    int logical = (bid & 7) * ((M_BOX * NCHUNK) / 8) + (bid >> 3);
    int m       = logical >> 3;
    int cbase   = (logical & 7) * CCH;

    int t = threadIdx.x;

    float4 bx = reinterpret_cast<const float4*>(boxes)[m];
    int bi = box_idx[m];
    float x1 = bx.x * INV_STRIDE;
    float y1 = bx.y * INV_STRIDE;
    float x2 = bx.z * INV_STRIDE;
    float y2 = bx.w * INV_STRIDE;

    // Window origin = taps of sample (0,0) (samples are monotonic in iy/ix).
    int xLo = min(max((int)floorf(x1), 0), W_DIM - 1);
    int yLo = min(max((int)floorf(y1), 0), H_DIM - 1);

    // ---- Phase A: stage 15x16 window of each plane into LDS ----
    if (t < WR * WC) {
        int r  = t >> 4;        // 0..14
        int cl = t & 15;        // 0..15
        int gy = min(yLo + r,  H_DIM - 1);
        int gx = min(xLo + cl, W_DIM - 1);
        const float* gsrc = fm + ((size_t)bi * C_DIM + cbase) * PLANE
                               + gy * W_DIM + gx;
        #pragma unroll
        for (int c = 0; c < CCH; ++c) {
            Wnd[c * WSZ + t] = gsrc[(size_t)c * PLANE];
        }
    }
    __syncthreads();

    // ---- Phase B: bilinear from LDS, one position per thread ----
    if (t < NPOS) {
        int iy = t / CW;
        int ix = t - iy * CW;

        // Match reference op order: v1 + (i * (v2-v1)) / 13
        float ys = y1 + ((float)iy * (y2 - y1)) / 13.0f;
        float xs = x1 + ((float)ix * (x2 - x1)) / 13.0f;

        float y0f = floorf(ys);
        float x0f = floorf(xs);
        float wy = ys - y0f;
        float wx = xs - x0f;
        float omwy = 1.0f - wy;
        float omwx = 1.0f - wx;

        int y0i = min(max((int)y0f, 0), H_DIM - 1);
        int y1i = min(y0i + 1, H_DIM - 1);
        int x0i = min(max((int)x0f, 0), W_DIM - 1);
        int x1i = min(x0i + 1, W_DIM - 1);

        bool valid = (ys >= 0.0f) && (ys <= (float)(H_DIM - 1)) &&
                     (xs >= 0.0f) && (xs <= (float)(W_DIM - 1));

        // Local window indices (proven in-range: tap - Lo <= 14)
        int w00 = (y0i - yLo) * WC + (x0i - xLo);
        int w01 = (y0i - yLo) * WC + (x1i - xLo);
        int w10 = (y1i - yLo) * WC + (x0i - xLo);
        int w11 = (y1i - yLo) * WC + (x1i - xLo);

        float* op = out + ((size_t)m * C_DIM + cbase) * NPOS + t;

        #pragma unroll 4
        for (int c = 0; c < CCH; ++c) {
            const float* w = &Wnd[c * WSZ];
            float f00 = w[w00];
            float f01 = w[w01];
            float f10 = w[w10];
            float f11 = w[w11];
            float top = f00 * omwx + f01 * wx;
            float bot = f10 * omwx + f11 * wx;
            float val = top * omwy + bot * wy;
            val = valid ? val : 0.0f;
            __builtin_nontemporal_store(val, op);
            op += NPOS;
        }
    }
}

extern "C" void kernel_launch(void* const* d_in, const int* in_sizes, int n_in,
                              void* d_out, int out_size, void* d_ws, size_t ws_size,
                              hipStream_t stream) {
    const float* fm      = (const float*)d_in[0];
    const float* boxes   = (const float*)d_in[1];
    const int*   box_idx = (const int*)d_in[2];
    float* out = (float*)d_out;

    dim3 block(256);
    dim3 grid(M_BOX * NCHUNK);  // 4096 blocks
    hipLaunchKernelGGL(roi_align_lds, grid, block, 0, stream,
                       fm, boxes, box_idx, out);
}